// Round 3
// baseline (987.120 us; speedup 1.0000x reference)
//
#include <hip/hip_runtime.h>
#include <hip/hip_bf16.h>
#include <cstddef>

#define N_USERS 50000
#define N_ITEMS 10000
#define N_NODES 100000
#define EMB 64
#define NNZ_E 1600000
#define VIS_DIM 2048
#define TXT_DIM 300

typedef short bf16x8 __attribute__((ext_vector_type(8)));
typedef float f32x4  __attribute__((ext_vector_type(4)));

__device__ inline unsigned short f2bf(float x) {
    __hip_bfloat16 h = __float2bfloat16(x);
    return __builtin_bit_cast(unsigned short, h);
}
__device__ inline float bf2f(unsigned short u) {
    unsigned int t = ((unsigned int)u) << 16;
    float f;
    __builtin_memcpy(&f, &t, 4);
    return f;
}

// ---------------------------------------------------------------------------
// gemm_dg: direct-global split-bf16 MFMA GEMM. No LDS, no barriers.
// Each wave owns an independent (MI*16)x(NI*16) output tile; A and W
// fragments are loaded straight from global (per-row 128B contiguous,
// L1/L2-served reuse), converted fp32->bf16 hi/lo in-register, and fed to
// mfma_f32_16x16x32_bf16 with the 3-term split (Ah*Wh + Ah*Wl + Al*Wh).
// Optional K-split via blockIdx.z: split z writes partial plane
// C + z*c_plane (bias only on plane 0); consumer sums planes.
// Rationale (R2 counters): previous 128x128 LDS kernel had 316 blocks ->
// 1.23 blocks/CU, Occupancy 11%, MfmaUtil 18% -- serialization-bound.
// This gives 2500+ independent waves and zero sync points.
// ---------------------------------------------------------------------------
template<int MI, int NI>
__global__ __launch_bounds__(256) void gemm_dg(
    const float* __restrict__ A, const float* __restrict__ W,
    const float* __restrict__ bias, float* __restrict__ C,
    int M, int N, int K, int k_per, long long c_plane,
    int act, int add_bias)
{
    const int t   = threadIdx.x;
    const int w   = t >> 6;
    const int l   = t & 63;
    const int l16 = l & 15;
    const int lq  = l >> 4;

    const int n0 = blockIdx.x * (NI * 16);
    const int m0 = (blockIdx.y * 4 + w) * (MI * 16);
    if (m0 >= M) return;
    const int kz = blockIdx.z;
    const int kb = kz * k_per;
    int krem = K - kb; if (krem > k_per) krem = k_per;
    const int kiters = (krem + 31) / 32;
    float* Cz = C + (long long)kz * c_plane;

    const float* ap[MI];
    #pragma unroll
    for (int mi = 0; mi < MI; mi++) {
        int r = m0 + mi * 16 + l16; if (r >= M) r = M - 1;
        ap[mi] = A + (size_t)r * K;
    }
    const float* wpt[NI];
    #pragma unroll
    for (int ni = 0; ni < NI; ni++) {
        int r = n0 + ni * 16 + l16; if (r >= N) r = N - 1;
        wpt[ni] = W + (size_t)r * K;
    }

    f32x4 acc[MI][NI] = {};

    for (int kt = 0; kt < kiters; kt++) {
        const int k0 = kb + kt * 32 + lq * 8;

        bf16x8 ahi[MI], alo[MI];
        #pragma unroll
        for (int mi = 0; mi < MI; mi++) {
            float v[8];
            if (k0 + 7 < K) {
                float4 q0 = *(const float4*)(ap[mi] + k0);
                float4 q1 = *(const float4*)(ap[mi] + k0 + 4);
                v[0]=q0.x; v[1]=q0.y; v[2]=q0.z; v[3]=q0.w;
                v[4]=q1.x; v[5]=q1.y; v[6]=q1.z; v[7]=q1.w;
            } else {
                #pragma unroll
                for (int i = 0; i < 8; i++)
                    v[i] = (k0 + i < K) ? ap[mi][k0 + i] : 0.f;
            }
            #pragma unroll
            for (int i = 0; i < 8; i++) {
                unsigned short h = f2bf(v[i]);
                ahi[mi][i] = (short)h;
                alo[mi][i] = (short)f2bf(v[i] - bf2f(h));
            }
        }

        bf16x8 whi[NI], wlo[NI];
        #pragma unroll
        for (int ni = 0; ni < NI; ni++) {
            float v[8];
            if (k0 + 7 < K) {
                float4 q0 = *(const float4*)(wpt[ni] + k0);
                float4 q1 = *(const float4*)(wpt[ni] + k0 + 4);
                v[0]=q0.x; v[1]=q0.y; v[2]=q0.z; v[3]=q0.w;
                v[4]=q1.x; v[5]=q1.y; v[6]=q1.z; v[7]=q1.w;
            } else {
                #pragma unroll
                for (int i = 0; i < 8; i++)
                    v[i] = (k0 + i < K) ? wpt[ni][k0 + i] : 0.f;
            }
            #pragma unroll
            for (int i = 0; i < 8; i++) {
                unsigned short h = f2bf(v[i]);
                whi[ni][i] = (short)h;
                wlo[ni][i] = (short)f2bf(v[i] - bf2f(h));
            }
        }

        #pragma unroll
        for (int ni = 0; ni < NI; ni++) {
            #pragma unroll
            for (int mi = 0; mi < MI; mi++) {
                acc[mi][ni] = __builtin_amdgcn_mfma_f32_16x16x32_bf16(
                    ahi[mi], whi[ni], acc[mi][ni], 0, 0, 0);
                acc[mi][ni] = __builtin_amdgcn_mfma_f32_16x16x32_bf16(
                    ahi[mi], wlo[ni], acc[mi][ni], 0, 0, 0);
                acc[mi][ni] = __builtin_amdgcn_mfma_f32_16x16x32_bf16(
                    alo[mi], whi[ni], acc[mi][ni], 0, 0, 0);
            }
        }
    }

    #pragma unroll
    for (int ni = 0; ni < NI; ni++) {
        int col = n0 + ni * 16 + l16;
        if (col >= N) continue;
        float b = (add_bias && kz == 0) ? bias[col] : 0.f;
        #pragma unroll
        for (int mi = 0; mi < MI; mi++) {
            #pragma unroll
            for (int r = 0; r < 4; r++) {
                int row = m0 + mi * 16 + lq * 4 + r;
                if (row >= M) continue;
                float vv = acc[mi][ni][r] + b;
                if (act) vv = fmaxf(vv, 0.f);
                Cz[(size_t)row * N + col] = vv;
            }
        }
    }
}

// ---------------------------------------------------------------------------
// concat_mfma: out[M,64] = leaky_relu([cur|nb][M,128] @ Wc[64,128]^T + bias)
// Split-bf16 3-term MFMA, TM=128, TN=64, BK=32, kiters=4.
// ---------------------------------------------------------------------------
#define GLDW 40

__global__ __launch_bounds__(256, 2) void concat_mfma(
    const float* __restrict__ cur, const float* __restrict__ nbuf,
    const float* __restrict__ Wc, const float* __restrict__ bias,
    float* __restrict__ out_cur, float* __restrict__ out_full, int col_off)
{
    __shared__ unsigned short Ah[128][GLDW], Al[128][GLDW];
    __shared__ unsigned short Bh[64][GLDW],  Bl[64][GLDW];

    const int t   = threadIdx.x;
    const int w   = t >> 6;
    const int l   = t & 63;
    const int l16 = l & 15;
    const int lq  = l >> 4;
    const int m0  = blockIdx.x * 128;
    const int mh  = w * 32;

    const int r  = t >> 2;
    const int kc = t & 3;

    f32x4 acc[2][4] = {};

    float pa[2][8], pw[8];

    auto load_tile = [&](int kt) {
        const float* src = (kt < 2) ? cur : nbuf;
        const int kcol = (kt & 1) * 32 + kc * 8;
        #pragma unroll
        for (int p = 0; p < 2; p++) {
            int rg = m0 + r + p * 64;
            if (rg >= N_NODES) rg = N_NODES - 1;
            const float* g = src + (size_t)rg * 64 + kcol;
            float4 q0 = *(const float4*)g, q1 = *(const float4*)(g + 4);
            pa[p][0]=q0.x; pa[p][1]=q0.y; pa[p][2]=q0.z; pa[p][3]=q0.w;
            pa[p][4]=q1.x; pa[p][5]=q1.y; pa[p][6]=q1.z; pa[p][7]=q1.w;
        }
        const float* gw = Wc + (size_t)r * 128 + kt * 32 + kc * 8;
        float4 q0 = *(const float4*)gw, q1 = *(const float4*)(gw + 4);
        pw[0]=q0.x; pw[1]=q0.y; pw[2]=q0.z; pw[3]=q0.w;
        pw[4]=q1.x; pw[5]=q1.y; pw[6]=q1.z; pw[7]=q1.w;
    };

    load_tile(0);

    for (int kt = 0; kt < 4; kt++) {
        #pragma unroll
        for (int p = 0; p < 2; p++) {
            bf16x8 hi, lo;
            #pragma unroll
            for (int i = 0; i < 8; i++) {
                unsigned short h = f2bf(pa[p][i]);
                hi[i] = (short)h;
                lo[i] = (short)f2bf(pa[p][i] - bf2f(h));
            }
            *(bf16x8*)&Ah[r + p * 64][kc * 8] = hi;
            *(bf16x8*)&Al[r + p * 64][kc * 8] = lo;
        }
        {
            bf16x8 hi, lo;
            #pragma unroll
            for (int i = 0; i < 8; i++) {
                unsigned short h = f2bf(pw[i]);
                hi[i] = (short)h;
                lo[i] = (short)f2bf(pw[i] - bf2f(h));
            }
            *(bf16x8*)&Bh[r][kc * 8] = hi;
            *(bf16x8*)&Bl[r][kc * 8] = lo;
        }
        __syncthreads();

        if (kt < 3) load_tile(kt + 1);

        {
            bf16x8 ah[2], al[2];
            #pragma unroll
            for (int mi = 0; mi < 2; mi++) {
                ah[mi] = *(const bf16x8*)&Ah[mh + mi * 16 + l16][lq * 8];
                al[mi] = *(const bf16x8*)&Al[mh + mi * 16 + l16][lq * 8];
            }
            #pragma unroll
            for (int ni = 0; ni < 4; ni++) {
                bf16x8 bh = *(const bf16x8*)&Bh[ni * 16 + l16][lq * 8];
                bf16x8 bl = *(const bf16x8*)&Bl[ni * 16 + l16][lq * 8];
                #pragma unroll
                for (int mi = 0; mi < 2; mi++) {
                    acc[mi][ni] = __builtin_amdgcn_mfma_f32_16x16x32_bf16(
                        ah[mi], bh, acc[mi][ni], 0, 0, 0);
                    acc[mi][ni] = __builtin_amdgcn_mfma_f32_16x16x32_bf16(
                        ah[mi], bl, acc[mi][ni], 0, 0, 0);
                    acc[mi][ni] = __builtin_amdgcn_mfma_f32_16x16x32_bf16(
                        al[mi], bh, acc[mi][ni], 0, 0, 0);
                }
            }
        }
        __syncthreads();
    }

    #pragma unroll
    for (int ni = 0; ni < 4; ni++) {
        int col = ni * 16 + l16;
        float bcol = bias[col];
        #pragma unroll
        for (int mi = 0; mi < 2; mi++) {
            #pragma unroll
            for (int rr = 0; rr < 4; rr++) {
                int row = m0 + mh + mi * 16 + lq * 4 + rr;
                if (row >= N_NODES) continue;
                float v = acc[mi][ni][rr] + bcol;
                v = (v > 0.f) ? v : 0.01f * v;
                if (out_cur) out_cur[(size_t)row * 64 + col] = v;
                out_full[(size_t)row * 192 + col_off + col] = v;
            }
        }
    }
}

// ---------------------------------------------------------------------------
__global__ void transp64(const float* __restrict__ W, float* __restrict__ wT, int K)
{
    int i = blockIdx.x * 256 + threadIdx.x;
    if (i >= 64 * K) return;
    int d = i / K, k = i - d * K;
    wT[k * 64 + d] = W[i];
}

// ---------------------------------------------------------------------------
// linear64 v3: out[M,64] = f(in [+ in2])[M,K] @ wT[K,64] * in_scale + bias.
// If fuse_relu: reads two partial planes (in, in2), sums them and applies
// relu on the fly (folds the vis GEMM's K-split + activation into this
// consumer -- no extra passes). 4 rows/wave, 16/block, float4 ILP.
// ---------------------------------------------------------------------------
__global__ __launch_bounds__(256) void linear64(
    const float* __restrict__ in, const float* __restrict__ in2,
    const float* __restrict__ wT, const float* __restrict__ bias,
    float* __restrict__ out, int M, int K, float in_scale, int add,
    int fuse_relu)
{
    int t  = threadIdx.x;
    int d  = t & 63;
    int w  = t >> 6;
    int m0 = blockIdx.x * 16 + w * 4;
    if (m0 >= M) return;
    int mlast = M - 1;
    int m1 = (m0 + 1 < M) ? m0 + 1 : mlast;
    int m2 = (m0 + 2 < M) ? m0 + 2 : mlast;
    int m3 = (m0 + 3 < M) ? m0 + 3 : mlast;

    const float* x0 = in + (size_t)m0 * K;
    const float* x1 = in + (size_t)m1 * K;
    const float* x2 = in + (size_t)m2 * K;
    const float* x3 = in + (size_t)m3 * K;
    const float* y0 = fuse_relu ? in2 + (size_t)m0 * K : x0;
    const float* y1 = fuse_relu ? in2 + (size_t)m1 * K : x1;
    const float* y2 = fuse_relu ? in2 + (size_t)m2 * K : x2;
    const float* y3 = fuse_relu ? in2 + (size_t)m3 * K : x3;

    float a0 = 0.f, a1 = 0.f, a2 = 0.f, a3 = 0.f;

    for (int k = 0; k < K; k += 8) {
        const float* wp = wT + (size_t)k * 64 + d;
        float w0 = wp[0],   w1 = wp[64],  w2 = wp[128], w3 = wp[192];
        float w4 = wp[256], w5 = wp[320], w6 = wp[384], w7 = wp[448];
        float4 p0 = *(const float4*)(x0 + k), q0 = *(const float4*)(x0 + k + 4);
        float4 p1 = *(const float4*)(x1 + k), q1 = *(const float4*)(x1 + k + 4);
        float4 p2 = *(const float4*)(x2 + k), q2 = *(const float4*)(x2 + k + 4);
        float4 p3 = *(const float4*)(x3 + k), q3 = *(const float4*)(x3 + k + 4);
        if (fuse_relu) {
            float4 r0 = *(const float4*)(y0 + k), s0 = *(const float4*)(y0 + k + 4);
            float4 r1 = *(const float4*)(y1 + k), s1 = *(const float4*)(y1 + k + 4);
            float4 r2 = *(const float4*)(y2 + k), s2 = *(const float4*)(y2 + k + 4);
            float4 r3 = *(const float4*)(y3 + k), s3 = *(const float4*)(y3 + k + 4);
            p0.x=fmaxf(p0.x+r0.x,0.f); p0.y=fmaxf(p0.y+r0.y,0.f);
            p0.z=fmaxf(p0.z+r0.z,0.f); p0.w=fmaxf(p0.w+r0.w,0.f);
            q0.x=fmaxf(q0.x+s0.x,0.f); q0.y=fmaxf(q0.y+s0.y,0.f);
            q0.z=fmaxf(q0.z+s0.z,0.f); q0.w=fmaxf(q0.w+s0.w,0.f);
            p1.x=fmaxf(p1.x+r1.x,0.f); p1.y=fmaxf(p1.y+r1.y,0.f);
            p1.z=fmaxf(p1.z+r1.z,0.f); p1.w=fmaxf(p1.w+r1.w,0.f);
            q1.x=fmaxf(q1.x+s1.x,0.f); q1.y=fmaxf(q1.y+s1.y,0.f);
            q1.z=fmaxf(q1.z+s1.z,0.f); q1.w=fmaxf(q1.w+s1.w,0.f);
            p2.x=fmaxf(p2.x+r2.x,0.f); p2.y=fmaxf(p2.y+r2.y,0.f);
            p2.z=fmaxf(p2.z+r2.z,0.f); p2.w=fmaxf(p2.w+r2.w,0.f);
            q2.x=fmaxf(q2.x+s2.x,0.f); q2.y=fmaxf(q2.y+s2.y,0.f);
            q2.z=fmaxf(q2.z+s2.z,0.f); q2.w=fmaxf(q2.w+s2.w,0.f);
            p3.x=fmaxf(p3.x+r3.x,0.f); p3.y=fmaxf(p3.y+r3.y,0.f);
            p3.z=fmaxf(p3.z+r3.z,0.f); p3.w=fmaxf(p3.w+r3.w,0.f);
            q3.x=fmaxf(q3.x+s3.x,0.f); q3.y=fmaxf(q3.y+s3.y,0.f);
            q3.z=fmaxf(q3.z+s3.z,0.f); q3.w=fmaxf(q3.w+s3.w,0.f);
        }
        a0 += p0.x*w0 + p0.y*w1 + p0.z*w2 + p0.w*w3
            + q0.x*w4 + q0.y*w5 + q0.z*w6 + q0.w*w7;
        a1 += p1.x*w0 + p1.y*w1 + p1.z*w2 + p1.w*w3
            + q1.x*w4 + q1.y*w5 + q1.z*w6 + q1.w*w7;
        a2 += p2.x*w0 + p2.y*w1 + p2.z*w2 + p2.w*w3
            + q2.x*w4 + q2.y*w5 + q2.z*w6 + q2.w*w7;
        a3 += p3.x*w0 + p3.y*w1 + p3.z*w2 + p3.w*w3
            + q3.x*w4 + q3.y*w5 + q3.z*w6 + q3.w*w7;
    }

    float b = bias[d];
    float r0 = a0 * in_scale + b;
    float r1 = a1 * in_scale + b;
    float r2 = a2 * in_scale + b;
    float r3 = a3 * in_scale + b;
    if (add) {
        out[(size_t)m0 * 64 + d] += r0;
        if (m0 + 1 < M) out[(size_t)m1 * 64 + d] += r1;
        if (m0 + 2 < M) out[(size_t)m2 * 64 + d] += r2;
        if (m0 + 3 < M) out[(size_t)m3 * 64 + d] += r3;
    } else {
        out[(size_t)m0 * 64 + d] = r0;
        if (m0 + 1 < M) out[(size_t)m1 * 64 + d] = r1;
        if (m0 + 2 < M) out[(size_t)m2 * 64 + d] = r2;
        if (m0 + 3 < M) out[(size_t)m3 * 64 + d] = r3;
    }
}

// ---------------------------------------------------------------------------
__global__ void ego_fill(const float* __restrict__ emb, float* __restrict__ cur0,
                         float* __restrict__ out_full)
{
    int tid = blockIdx.x * 256 + threadIdx.x;
    if (tid >= N_NODES * EMB) return;
    int m = tid >> 6, d = tid & 63;
    float v;
    if (m < N_USERS || m >= N_USERS + N_ITEMS) {
        v = emb[tid];
        cur0[tid] = v;
    } else {
        v = cur0[tid];
    }
    out_full[(size_t)m * 192 + d] = v;
}

// ---------------------------------------------------------------------------
// CSR build: histogram -> exclusive scan -> scatter
// ---------------------------------------------------------------------------
__global__ __launch_bounds__(256) void hist_rows(
    const int* __restrict__ row, int* __restrict__ cnt, int nnz)
{
    int e = blockIdx.x * 256 + threadIdx.x;
    if (e >= nnz) return;
    atomicAdd(&cnt[row[e]], 1);
}

__global__ __launch_bounds__(256) void scan1(int* __restrict__ cnt,
                                             int* __restrict__ bsum, int n)
{
    __shared__ int part[256];
    int t = threadIdx.x;
    int base = blockIdx.x * 1024 + t * 4;
    int v0 = 0, v1 = 0, v2 = 0, v3 = 0;
    if (base + 0 < n) v0 = cnt[base + 0];
    if (base + 1 < n) v1 = cnt[base + 1];
    if (base + 2 < n) v2 = cnt[base + 2];
    if (base + 3 < n) v3 = cnt[base + 3];
    int s = v0 + v1 + v2 + v3;
    part[t] = s;
    __syncthreads();
    for (int off = 1; off < 256; off <<= 1) {
        int x = (t >= off) ? part[t - off] : 0;
        __syncthreads();
        part[t] += x;
        __syncthreads();
    }
    int excl = part[t] - s;
    if (t == 255) bsum[blockIdx.x] = part[t];
    if (base + 0 < n) cnt[base + 0] = excl;
    if (base + 1 < n) cnt[base + 1] = excl + v0;
    if (base + 2 < n) cnt[base + 2] = excl + v0 + v1;
    if (base + 3 < n) cnt[base + 3] = excl + v0 + v1 + v2;
}

__global__ void scan2(int* __restrict__ bsum, int nb)
{
    if (threadIdx.x == 0 && blockIdx.x == 0) {
        int acc = 0;
        for (int i = 0; i < nb; i++) { int v = bsum[i]; bsum[i] = acc; acc += v; }
    }
}

__global__ __launch_bounds__(256) void scan3(
    const int* __restrict__ excl, const int* __restrict__ bsum,
    int* __restrict__ row_ptr, int* __restrict__ row_cur, int n, int nnz)
{
    int i = blockIdx.x * 256 + threadIdx.x;
    if (i > n) return;
    if (i == n) { row_ptr[n] = nnz; return; }
    int v = excl[i] + bsum[i >> 10];
    row_ptr[i] = v;
    row_cur[i] = v;
}

__global__ __launch_bounds__(256) void scatter_csr(
    const int* __restrict__ row, const int* __restrict__ col,
    const float* __restrict__ val, int* __restrict__ row_cur,
    int* __restrict__ col_s, float* __restrict__ val_s, int nnz)
{
    int e = blockIdx.x * 256 + threadIdx.x;
    if (e >= nnz) return;
    int r = row[e];
    int p = atomicAdd(&row_cur[r], 1);
    col_s[p] = col[e];
    val_s[p] = val[e];
}

// ---------------------------------------------------------------------------
// Gather SpMM: one wave per row; 64 lanes = 4 edge-slots x 16 dim-groups.
// ---------------------------------------------------------------------------
__global__ __launch_bounds__(256) void spmm_gather(
    const int* __restrict__ row_ptr, const int* __restrict__ col_s,
    const float* __restrict__ val_s, const float* __restrict__ cur,
    float* __restrict__ nb)
{
    int t  = threadIdx.x;
    int wv = t >> 6;
    int l  = t & 63;
    int eg = l >> 4;          // edge slot 0..3
    int dg = l & 15;          // dim group (4 floats)
    int m = blockIdx.x * 4 + wv;
    if (m >= N_NODES) return;
    int beg = row_ptr[m], end = row_ptr[m + 1];
    float ax = 0.f, ay = 0.f, az = 0.f, aw = 0.f;
    for (int j = beg + eg; j < end; j += 4) {
        int   c = col_s[j];
        float v = val_s[j];
        float4 cv = *(const float4*)&cur[(size_t)c * 64 + dg * 4];
        ax += v * cv.x; ay += v * cv.y; az += v * cv.z; aw += v * cv.w;
    }
    ax += __shfl_xor(ax, 16, 64); ay += __shfl_xor(ay, 16, 64);
    az += __shfl_xor(az, 16, 64); aw += __shfl_xor(aw, 16, 64);
    ax += __shfl_xor(ax, 32, 64); ay += __shfl_xor(ay, 32, 64);
    az += __shfl_xor(az, 32, 64); aw += __shfl_xor(aw, 32, 64);
    if (eg == 0) {
        float4 r; r.x = ax; r.y = ay; r.z = az; r.w = aw;
        *(float4*)&nb[(size_t)m * 64 + dg * 4] = r;
    }
}

// ---------------------------------------------------------------------------
extern "C" void kernel_launch(void* const* d_in, const int* in_sizes, int n_in,
                              void* d_out, int out_size, void* d_ws, size_t ws_size,
                              hipStream_t stream)
{
    const int*   adj_row = (const int*)  d_in[0];
    const int*   adj_col = (const int*)  d_in[1];
    const float* adj_val = (const float*)d_in[2];
    const float* emb     = (const float*)d_in[3];
    const float* visf    = (const float*)d_in[4];
    const float* txtf    = (const float*)d_in[5];
    const float* Wv1 = (const float*)d_in[6];  const float* bv1 = (const float*)d_in[7];
    const float* Wv2 = (const float*)d_in[8];  const float* bv2 = (const float*)d_in[9];
    const float* Wt1 = (const float*)d_in[10]; const float* bt1 = (const float*)d_in[11];
    const float* Wt2 = (const float*)d_in[12]; const float* bt2 = (const float*)d_in[13];
    const float* Wd  = (const float*)d_in[14]; const float* bd  = (const float*)d_in[15];
    const float* Wc0 = (const float*)d_in[16]; const float* bc0 = (const float*)d_in[17];
    const float* Wc1 = (const float*)d_in[18]; const float* bc1 = (const float*)d_in[19];

    float* out = (float*)d_out;
    float* ws  = (float*)d_ws;

    // workspace layout (float offsets) — proven size, H1v2 aliases cur1
    float* H1v  = ws + 0;          // 10000*512
    float* H1t  = ws + 5120000;    // 10000*256
    float* nb   = ws + 0;          // 100000*64 (reuses H1v region, after MLP)
    float* s    = ws + 7680000;    // 10000*64
    float* cur0 = ws + 8320000;    // 100000*64
    float* cur1 = ws + 14720000;   // 100000*64
    float* H1v2 = ws + 14720000;   // 10000*512 partial plane 2 (aliases cur1;
                                   // consumed by linear64-vis BEFORE concat
                                   // layer1 writes cur1 -- stream-ordered)
    float* wv2T = ws + 21120000;   // 512*64
    float* wt2T = wv2T + 32768;    // 256*64
    float* wdT  = wt2T + 16384;    // 64*64
    int*   col_s   = (int*)  (ws + 21200000);  // 1.6M
    float* val_s   =          ws + 22800000;   // 1.6M
    int*   row_ptr = (int*)  (ws + 24400000);  // 100001
    int*   row_cur = (int*)  (ws + 24510000);  // 100000
    int*   cnt     = (int*)  (ws + 24620000);  // 100000
    int*   bsum    = (int*)  (ws + 24730000);  // 98

    const int NBLK = (N_NODES + 1023) / 1024;  // 98

    // ---- weight transposes (tiny) ----
    transp64<<<(64 * 512 + 255) / 256, 256, 0, stream>>>(Wv2, wv2T, 512);
    transp64<<<(64 * 256 + 255) / 256, 256, 0, stream>>>(Wt2, wt2T, 256);
    transp64<<<(64 * 64  + 255) / 256, 256, 0, stream>>>(Wd,  wdT,  64);

    // ---- CSR build (reused for both propagation layers) ----
    hipMemsetAsync(cnt, 0, N_NODES * sizeof(int), stream);
    hist_rows<<<(NNZ_E + 255) / 256, 256, 0, stream>>>(adj_row, cnt, NNZ_E);
    scan1<<<NBLK, 256, 0, stream>>>(cnt, bsum, N_NODES);
    scan2<<<1, 64, 0, stream>>>(bsum, NBLK);
    scan3<<<(N_NODES + 256) / 256, 256, 0, stream>>>(cnt, bsum, row_ptr, row_cur,
                                                     N_NODES, NNZ_E);
    scatter_csr<<<(NNZ_E + 255) / 256, 256, 0, stream>>>(adj_row, adj_col, adj_val,
                                                         row_cur, col_s, val_s, NNZ_E);

    // ---- item MLP layer 1: direct-global MFMA GEMMs ----
    {
        // vis: M=10000 N=512 K=2048; 64x64 wave tiles, K split in 2 planes.
        // grid: 8 n-tiles x ceil(157/4) x 2 splits = 2560 waves (~2.5/SIMD)
        dim3 g(512 / 64, (157 + 3) / 4, 2);
        gemm_dg<4, 4><<<g, 256, 0, stream>>>(visf, Wv1, bv1, H1v,
                                             N_ITEMS, 512, VIS_DIM,
                                             1024, (long long)14720000,
                                             0, 1);
    }
    {
        // txt: M=10000 N=256 K=300; 32x32 wave tiles, no split, relu+bias here.
        dim3 g(256 / 32, (313 + 3) / 4, 1);
        gemm_dg<2, 2><<<g, 256, 0, stream>>>(txtf, Wt1, bt1, H1t,
                                             N_ITEMS, 256, TXT_DIM,
                                             512, 0, 1, 1);
    }

    // ---- layer 2 + shared Wd (vis: fuse plane-sum + relu into consumer) ----
    linear64<<<(N_ITEMS + 15) / 16, 256, 0, stream>>>(H1v, H1v2, wv2T, bv2, s,
                                                      N_ITEMS, 512, 1.0f, 0, 1);
    linear64<<<(N_ITEMS + 15) / 16, 256, 0, stream>>>(H1t, nullptr, wt2T, bt2, s,
                                                      N_ITEMS, 256, 1.0f, 1, 0);
    linear64<<<(N_ITEMS + 15) / 16, 256, 0, stream>>>(s, nullptr, wdT, bd,
                                                      cur0 + (size_t)N_USERS * 64,
                                                      N_ITEMS, 64, 0.5f, 0, 0);

    // ---- assemble ego, write out[:, 0:64] ----
    ego_fill<<<(N_NODES * EMB + 255) / 256, 256, 0, stream>>>(emb, cur0, out);

    // ---- propagation layer 1 (gather SpMM + MFMA concat-linear) ----
    spmm_gather<<<(N_NODES + 3) / 4, 256, 0, stream>>>(row_ptr, col_s, val_s, cur0, nb);
    concat_mfma<<<(N_NODES + 127) / 128, 256, 0, stream>>>(cur0, nb, Wc0, bc0, cur1, out, 64);

    // ---- propagation layer 2 ----
    spmm_gather<<<(N_NODES + 3) / 4, 256, 0, stream>>>(row_ptr, col_s, val_s, cur1, nb);
    concat_mfma<<<(N_NODES + 127) / 128, 256, 0, stream>>>(cur1, nb, Wc1, bc1, nullptr, out, 128);
}

// Round 4
// 831.258 us; speedup vs baseline: 1.1875x; 1.1875x over previous
//
#include <hip/hip_runtime.h>
#include <hip/hip_bf16.h>
#include <cstddef>

#define N_USERS 50000
#define N_ITEMS 10000
#define N_NODES 100000
#define EMB 64
#define NNZ_E 1600000
#define VIS_DIM 2048
#define TXT_DIM 300

typedef short bf16x8 __attribute__((ext_vector_type(8)));
typedef float f32x4  __attribute__((ext_vector_type(4)));

__device__ inline unsigned short f2bf(float x) {
    __hip_bfloat16 h = __float2bfloat16(x);
    return __builtin_bit_cast(unsigned short, h);
}
__device__ inline float bf2f(unsigned short u) {
    unsigned int t = ((unsigned int)u) << 16;
    float f;
    __builtin_memcpy(&f, &t, 4);
    return f;
}

#define GLDW 40

// ---------------------------------------------------------------------------
// gemm_bf64: split-bf16 MFMA GEMM, C = act(A[M,K] @ W[N,K]^T + bias).
// TM=128, TN=64, BK=32. LDS-staged (KEEPS the data reuse that gemm_dg lost:
// R3 post-mortem showed no-LDS tripled FETCH_SIZE 165->324 MB and regressed
// 135->299us). 4 waves stacked in M, each wave 32x64 as 2x4 frags of
// mfma_f32_16x16x32_bf16, 3-term split (Ah*Wh + Ah*Wl + Al*Wh).
// Occupancy fix vs R2's 128x128 kernel (316 blocks, Occ 11%, MfmaUtil 18%):
// half-width tiles + optional K-split via blockIdx.z -> 4x the blocks,
// LDS 40960->30720 B, 2 blocks/CU resident so barrier stalls overlap.
// K-split: plane z writes C + z*c_plane (bias only on z==0, act must be 0);
// consumer (linear64 fuse path) sums planes + applies relu.
// ---------------------------------------------------------------------------
__global__ __launch_bounds__(256, 2) void gemm_bf64(
    const float* __restrict__ A, const float* __restrict__ W,
    const float* __restrict__ bias, float* __restrict__ C,
    int M, int N, int K, int k_per, long long c_plane,
    int act, int add_bias)
{
    __shared__ unsigned short Ah[128][GLDW], Al[128][GLDW];
    __shared__ unsigned short Bh[64][GLDW],  Bl[64][GLDW];

    const int t   = threadIdx.x;
    const int w   = t >> 6;
    const int l   = t & 63;
    const int l16 = l & 15;
    const int lq  = l >> 4;
    const int n0  = blockIdx.x * 64;
    const int m0  = blockIdx.y * 128;
    const int mh  = w * 32;

    const int kz  = blockIdx.z;
    const int kb  = kz * k_per;
    int krem = K - kb; if (krem > k_per) krem = k_per;
    const int kiters = (krem + 31) / 32;
    const int kend = kb + krem;
    float* Cz = C + (long long)kz * c_plane;

    // staging: A rows via chunks t (rows 0..63) and t+256 (rows 64..127);
    // W rows 0..63, one chunk per thread. 8 consecutive k-elems per chunk.
    const int rA0 = t >> 2;
    const int rA1 = (t + 256) >> 2;
    const int kc  = t & 3;

    f32x4 acc[2][4] = {};
    float pa[2][8], pw[8];

    auto load_tile = [&](int kt) {
        const int k0 = kb + kt * 32 + kc * 8;
        #pragma unroll
        for (int p = 0; p < 2; p++) {
            int rg = m0 + (p ? rA1 : rA0);
            if (rg >= M) rg = M - 1;
            const float* g = A + (size_t)rg * K + k0;
            if (k0 + 7 < kend) {
                float4 q0 = *(const float4*)g, q1 = *(const float4*)(g + 4);
                pa[p][0]=q0.x; pa[p][1]=q0.y; pa[p][2]=q0.z; pa[p][3]=q0.w;
                pa[p][4]=q1.x; pa[p][5]=q1.y; pa[p][6]=q1.z; pa[p][7]=q1.w;
            } else {
                #pragma unroll
                for (int i = 0; i < 8; i++)
                    pa[p][i] = (k0 + i < kend) ? g[i] : 0.f;
            }
        }
        int ng = n0 + rA0;
        if (ng >= N) ng = N - 1;
        const float* gw = W + (size_t)ng * K + k0;
        if (k0 + 7 < kend) {
            float4 q0 = *(const float4*)gw, q1 = *(const float4*)(gw + 4);
            pw[0]=q0.x; pw[1]=q0.y; pw[2]=q0.z; pw[3]=q0.w;
            pw[4]=q1.x; pw[5]=q1.y; pw[6]=q1.z; pw[7]=q1.w;
        } else {
            #pragma unroll
            for (int i = 0; i < 8; i++)
                pw[i] = (k0 + i < kend) ? gw[i] : 0.f;
        }
    };

    load_tile(0);

    for (int kt = 0; kt < kiters; kt++) {
        // ---- convert prefetched regs -> LDS hi/lo ----
        #pragma unroll
        for (int p = 0; p < 2; p++) {
            int row = p ? rA1 : rA0;
            bf16x8 hi, lo;
            #pragma unroll
            for (int i = 0; i < 8; i++) {
                unsigned short h = f2bf(pa[p][i]);
                hi[i] = (short)h;
                lo[i] = (short)f2bf(pa[p][i] - bf2f(h));
            }
            *(bf16x8*)&Ah[row][kc * 8] = hi;
            *(bf16x8*)&Al[row][kc * 8] = lo;
        }
        {
            bf16x8 hi, lo;
            #pragma unroll
            for (int i = 0; i < 8; i++) {
                unsigned short h = f2bf(pw[i]);
                hi[i] = (short)h;
                lo[i] = (short)f2bf(pw[i] - bf2f(h));
            }
            *(bf16x8*)&Bh[rA0][kc * 8] = hi;
            *(bf16x8*)&Bl[rA0][kc * 8] = lo;
        }
        __syncthreads();

        // ---- issue next tile's global loads (overlap with MFMA) ----
        if (kt + 1 < kiters) load_tile(kt + 1);

        // ---- MFMA: 2x4 frags x 3 split terms ----
        {
            bf16x8 ah[2], al[2];
            #pragma unroll
            for (int mi = 0; mi < 2; mi++) {
                ah[mi] = *(const bf16x8*)&Ah[mh + mi * 16 + l16][lq * 8];
                al[mi] = *(const bf16x8*)&Al[mh + mi * 16 + l16][lq * 8];
            }
            #pragma unroll
            for (int ni = 0; ni < 4; ni++) {
                bf16x8 bh = *(const bf16x8*)&Bh[ni * 16 + l16][lq * 8];
                bf16x8 bl = *(const bf16x8*)&Bl[ni * 16 + l16][lq * 8];
                #pragma unroll
                for (int mi = 0; mi < 2; mi++) {
                    acc[mi][ni] = __builtin_amdgcn_mfma_f32_16x16x32_bf16(
                        ah[mi], bh, acc[mi][ni], 0, 0, 0);
                    acc[mi][ni] = __builtin_amdgcn_mfma_f32_16x16x32_bf16(
                        ah[mi], bl, acc[mi][ni], 0, 0, 0);
                    acc[mi][ni] = __builtin_amdgcn_mfma_f32_16x16x32_bf16(
                        al[mi], bh, acc[mi][ni], 0, 0, 0);
                }
            }
        }
        __syncthreads();
    }

    // ---- epilogue ----
    #pragma unroll
    for (int ni = 0; ni < 4; ni++) {
        int col = n0 + ni * 16 + l16;
        if (col >= N) continue;
        float b = (add_bias && kz == 0) ? bias[col] : 0.f;
        #pragma unroll
        for (int mi = 0; mi < 2; mi++) {
            #pragma unroll
            for (int r = 0; r < 4; r++) {
                int row = m0 + mh + mi * 16 + lq * 4 + r;
                if (row >= M) continue;
                float v = acc[mi][ni][r] + b;
                if (act) v = fmaxf(v, 0.f);
                Cz[(size_t)row * N + col] = v;
            }
        }
    }
}

// ---------------------------------------------------------------------------
// concat_mfma: out[M,64] = leaky_relu([cur|nb][M,128] @ Wc[64,128]^T + bias)
// Split-bf16 3-term MFMA, TM=128, TN=64, BK=32, kiters=4.
// ---------------------------------------------------------------------------
__global__ __launch_bounds__(256, 2) void concat_mfma(
    const float* __restrict__ cur, const float* __restrict__ nbuf,
    const float* __restrict__ Wc, const float* __restrict__ bias,
    float* __restrict__ out_cur, float* __restrict__ out_full, int col_off)
{
    __shared__ unsigned short Ah[128][GLDW], Al[128][GLDW];
    __shared__ unsigned short Bh[64][GLDW],  Bl[64][GLDW];

    const int t   = threadIdx.x;
    const int w   = t >> 6;
    const int l   = t & 63;
    const int l16 = l & 15;
    const int lq  = l >> 4;
    const int m0  = blockIdx.x * 128;
    const int mh  = w * 32;

    const int r  = t >> 2;
    const int kc = t & 3;

    f32x4 acc[2][4] = {};

    float pa[2][8], pw[8];

    auto load_tile = [&](int kt) {
        const float* src = (kt < 2) ? cur : nbuf;
        const int kcol = (kt & 1) * 32 + kc * 8;
        #pragma unroll
        for (int p = 0; p < 2; p++) {
            int rg = m0 + r + p * 64;
            if (rg >= N_NODES) rg = N_NODES - 1;
            const float* g = src + (size_t)rg * 64 + kcol;
            float4 q0 = *(const float4*)g, q1 = *(const float4*)(g + 4);
            pa[p][0]=q0.x; pa[p][1]=q0.y; pa[p][2]=q0.z; pa[p][3]=q0.w;
            pa[p][4]=q1.x; pa[p][5]=q1.y; pa[p][6]=q1.z; pa[p][7]=q1.w;
        }
        const float* gw = Wc + (size_t)r * 128 + kt * 32 + kc * 8;
        float4 q0 = *(const float4*)gw, q1 = *(const float4*)(gw + 4);
        pw[0]=q0.x; pw[1]=q0.y; pw[2]=q0.z; pw[3]=q0.w;
        pw[4]=q1.x; pw[5]=q1.y; pw[6]=q1.z; pw[7]=q1.w;
    };

    load_tile(0);

    for (int kt = 0; kt < 4; kt++) {
        #pragma unroll
        for (int p = 0; p < 2; p++) {
            bf16x8 hi, lo;
            #pragma unroll
            for (int i = 0; i < 8; i++) {
                unsigned short h = f2bf(pa[p][i]);
                hi[i] = (short)h;
                lo[i] = (short)f2bf(pa[p][i] - bf2f(h));
            }
            *(bf16x8*)&Ah[r + p * 64][kc * 8] = hi;
            *(bf16x8*)&Al[r + p * 64][kc * 8] = lo;
        }
        {
            bf16x8 hi, lo;
            #pragma unroll
            for (int i = 0; i < 8; i++) {
                unsigned short h = f2bf(pw[i]);
                hi[i] = (short)h;
                lo[i] = (short)f2bf(pw[i] - bf2f(h));
            }
            *(bf16x8*)&Bh[r][kc * 8] = hi;
            *(bf16x8*)&Bl[r][kc * 8] = lo;
        }
        __syncthreads();

        if (kt < 3) load_tile(kt + 1);

        {
            bf16x8 ah[2], al[2];
            #pragma unroll
            for (int mi = 0; mi < 2; mi++) {
                ah[mi] = *(const bf16x8*)&Ah[mh + mi * 16 + l16][lq * 8];
                al[mi] = *(const bf16x8*)&Al[mh + mi * 16 + l16][lq * 8];
            }
            #pragma unroll
            for (int ni = 0; ni < 4; ni++) {
                bf16x8 bh = *(const bf16x8*)&Bh[ni * 16 + l16][lq * 8];
                bf16x8 bl = *(const bf16x8*)&Bl[ni * 16 + l16][lq * 8];
                #pragma unroll
                for (int mi = 0; mi < 2; mi++) {
                    acc[mi][ni] = __builtin_amdgcn_mfma_f32_16x16x32_bf16(
                        ah[mi], bh, acc[mi][ni], 0, 0, 0);
                    acc[mi][ni] = __builtin_amdgcn_mfma_f32_16x16x32_bf16(
                        ah[mi], bl, acc[mi][ni], 0, 0, 0);
                    acc[mi][ni] = __builtin_amdgcn_mfma_f32_16x16x32_bf16(
                        al[mi], bh, acc[mi][ni], 0, 0, 0);
                }
            }
        }
        __syncthreads();
    }

    #pragma unroll
    for (int ni = 0; ni < 4; ni++) {
        int col = ni * 16 + l16;
        float bcol = bias[col];
        #pragma unroll
        for (int mi = 0; mi < 2; mi++) {
            #pragma unroll
            for (int rr = 0; rr < 4; rr++) {
                int row = m0 + mh + mi * 16 + lq * 4 + rr;
                if (row >= N_NODES) continue;
                float v = acc[mi][ni][rr] + bcol;
                v = (v > 0.f) ? v : 0.01f * v;
                if (out_cur) out_cur[(size_t)row * 64 + col] = v;
                out_full[(size_t)row * 192 + col_off + col] = v;
            }
        }
    }
}

// ---------------------------------------------------------------------------
__global__ void transp64(const float* __restrict__ W, float* __restrict__ wT, int K)
{
    int i = blockIdx.x * 256 + threadIdx.x;
    if (i >= 64 * K) return;
    int d = i / K, k = i - d * K;
    wT[k * 64 + d] = W[i];
}

// ---------------------------------------------------------------------------
// linear64 v3: out[M,64] = f(in [+ in2])[M,K] @ wT[K,64] * in_scale + bias.
// fuse_relu: sums two partial K-split planes and applies relu on the fly.
// ---------------------------------------------------------------------------
__global__ __launch_bounds__(256) void linear64(
    const float* __restrict__ in, const float* __restrict__ in2,
    const float* __restrict__ wT, const float* __restrict__ bias,
    float* __restrict__ out, int M, int K, float in_scale, int add,
    int fuse_relu)
{
    int t  = threadIdx.x;
    int d  = t & 63;
    int w  = t >> 6;
    int m0 = blockIdx.x * 16 + w * 4;
    if (m0 >= M) return;
    int mlast = M - 1;
    int m1 = (m0 + 1 < M) ? m0 + 1 : mlast;
    int m2 = (m0 + 2 < M) ? m0 + 2 : mlast;
    int m3 = (m0 + 3 < M) ? m0 + 3 : mlast;

    const float* x0 = in + (size_t)m0 * K;
    const float* x1 = in + (size_t)m1 * K;
    const float* x2 = in + (size_t)m2 * K;
    const float* x3 = in + (size_t)m3 * K;
    const float* y0 = fuse_relu ? in2 + (size_t)m0 * K : x0;
    const float* y1 = fuse_relu ? in2 + (size_t)m1 * K : x1;
    const float* y2 = fuse_relu ? in2 + (size_t)m2 * K : x2;
    const float* y3 = fuse_relu ? in2 + (size_t)m3 * K : x3;

    float a0 = 0.f, a1 = 0.f, a2 = 0.f, a3 = 0.f;

    for (int k = 0; k < K; k += 8) {
        const float* wp = wT + (size_t)k * 64 + d;
        float w0 = wp[0],   w1 = wp[64],  w2 = wp[128], w3 = wp[192];
        float w4 = wp[256], w5 = wp[320], w6 = wp[384], w7 = wp[448];
        float4 p0 = *(const float4*)(x0 + k), q0 = *(const float4*)(x0 + k + 4);
        float4 p1 = *(const float4*)(x1 + k), q1 = *(const float4*)(x1 + k + 4);
        float4 p2 = *(const float4*)(x2 + k), q2 = *(const float4*)(x2 + k + 4);
        float4 p3 = *(const float4*)(x3 + k), q3 = *(const float4*)(x3 + k + 4);
        if (fuse_relu) {
            float4 r0 = *(const float4*)(y0 + k), s0 = *(const float4*)(y0 + k + 4);
            float4 r1 = *(const float4*)(y1 + k), s1 = *(const float4*)(y1 + k + 4);
            float4 r2 = *(const float4*)(y2 + k), s2 = *(const float4*)(y2 + k + 4);
            float4 r3 = *(const float4*)(y3 + k), s3 = *(const float4*)(y3 + k + 4);
            p0.x=fmaxf(p0.x+r0.x,0.f); p0.y=fmaxf(p0.y+r0.y,0.f);
            p0.z=fmaxf(p0.z+r0.z,0.f); p0.w=fmaxf(p0.w+r0.w,0.f);
            q0.x=fmaxf(q0.x+s0.x,0.f); q0.y=fmaxf(q0.y+s0.y,0.f);
            q0.z=fmaxf(q0.z+s0.z,0.f); q0.w=fmaxf(q0.w+s0.w,0.f);
            p1.x=fmaxf(p1.x+r1.x,0.f); p1.y=fmaxf(p1.y+r1.y,0.f);
            p1.z=fmaxf(p1.z+r1.z,0.f); p1.w=fmaxf(p1.w+r1.w,0.f);
            q1.x=fmaxf(q1.x+s1.x,0.f); q1.y=fmaxf(q1.y+s1.y,0.f);
            q1.z=fmaxf(q1.z+s1.z,0.f); q1.w=fmaxf(q1.w+s1.w,0.f);
            p2.x=fmaxf(p2.x+r2.x,0.f); p2.y=fmaxf(p2.y+r2.y,0.f);
            p2.z=fmaxf(p2.z+r2.z,0.f); p2.w=fmaxf(p2.w+r2.w,0.f);
            q2.x=fmaxf(q2.x+s2.x,0.f); q2.y=fmaxf(q2.y+s2.y,0.f);
            q2.z=fmaxf(q2.z+s2.z,0.f); q2.w=fmaxf(q2.w+s2.w,0.f);
            p3.x=fmaxf(p3.x+r3.x,0.f); p3.y=fmaxf(p3.y+r3.y,0.f);
            p3.z=fmaxf(p3.z+r3.z,0.f); p3.w=fmaxf(p3.w+r3.w,0.f);
            q3.x=fmaxf(q3.x+s3.x,0.f); q3.y=fmaxf(q3.y+s3.y,0.f);
            q3.z=fmaxf(q3.z+s3.z,0.f); q3.w=fmaxf(q3.w+s3.w,0.f);
        }
        a0 += p0.x*w0 + p0.y*w1 + p0.z*w2 + p0.w*w3
            + q0.x*w4 + q0.y*w5 + q0.z*w6 + q0.w*w7;
        a1 += p1.x*w0 + p1.y*w1 + p1.z*w2 + p1.w*w3
            + q1.x*w4 + q1.y*w5 + q1.z*w6 + q1.w*w7;
        a2 += p2.x*w0 + p2.y*w1 + p2.z*w2 + p2.w*w3
            + q2.x*w4 + q2.y*w5 + q2.z*w6 + q2.w*w7;
        a3 += p3.x*w0 + p3.y*w1 + p3.z*w2 + p3.w*w3
            + q3.x*w4 + q3.y*w5 + q3.z*w6 + q3.w*w7;
    }

    float b = bias[d];
    float r0 = a0 * in_scale + b;
    float r1 = a1 * in_scale + b;
    float r2 = a2 * in_scale + b;
    float r3 = a3 * in_scale + b;
    if (add) {
        out[(size_t)m0 * 64 + d] += r0;
        if (m0 + 1 < M) out[(size_t)m1 * 64 + d] += r1;
        if (m0 + 2 < M) out[(size_t)m2 * 64 + d] += r2;
        if (m0 + 3 < M) out[(size_t)m3 * 64 + d] += r3;
    } else {
        out[(size_t)m0 * 64 + d] = r0;
        if (m0 + 1 < M) out[(size_t)m1 * 64 + d] = r1;
        if (m0 + 2 < M) out[(size_t)m2 * 64 + d] = r2;
        if (m0 + 3 < M) out[(size_t)m3 * 64 + d] = r3;
    }
}

// ---------------------------------------------------------------------------
__global__ void ego_fill(const float* __restrict__ emb, float* __restrict__ cur0,
                         float* __restrict__ out_full)
{
    int tid = blockIdx.x * 256 + threadIdx.x;
    if (tid >= N_NODES * EMB) return;
    int m = tid >> 6, d = tid & 63;
    float v;
    if (m < N_USERS || m >= N_USERS + N_ITEMS) {
        v = emb[tid];
        cur0[tid] = v;
    } else {
        v = cur0[tid];
    }
    out_full[(size_t)m * 192 + d] = v;
}

// ---------------------------------------------------------------------------
// CSR build: histogram -> exclusive scan -> scatter
// ---------------------------------------------------------------------------
__global__ __launch_bounds__(256) void hist_rows(
    const int* __restrict__ row, int* __restrict__ cnt, int nnz)
{
    int e = blockIdx.x * 256 + threadIdx.x;
    if (e >= nnz) return;
    atomicAdd(&cnt[row[e]], 1);
}

__global__ __launch_bounds__(256) void scan1(int* __restrict__ cnt,
                                             int* __restrict__ bsum, int n)
{
    __shared__ int part[256];
    int t = threadIdx.x;
    int base = blockIdx.x * 1024 + t * 4;
    int v0 = 0, v1 = 0, v2 = 0, v3 = 0;
    if (base + 0 < n) v0 = cnt[base + 0];
    if (base + 1 < n) v1 = cnt[base + 1];
    if (base + 2 < n) v2 = cnt[base + 2];
    if (base + 3 < n) v3 = cnt[base + 3];
    int s = v0 + v1 + v2 + v3;
    part[t] = s;
    __syncthreads();
    for (int off = 1; off < 256; off <<= 1) {
        int x = (t >= off) ? part[t - off] : 0;
        __syncthreads();
        part[t] += x;
        __syncthreads();
    }
    int excl = part[t] - s;
    if (t == 255) bsum[blockIdx.x] = part[t];
    if (base + 0 < n) cnt[base + 0] = excl;
    if (base + 1 < n) cnt[base + 1] = excl + v0;
    if (base + 2 < n) cnt[base + 2] = excl + v0 + v1;
    if (base + 3 < n) cnt[base + 3] = excl + v0 + v1 + v2;
}

__global__ void scan2(int* __restrict__ bsum, int nb)
{
    if (threadIdx.x == 0 && blockIdx.x == 0) {
        int acc = 0;
        for (int i = 0; i < nb; i++) { int v = bsum[i]; bsum[i] = acc; acc += v; }
    }
}

__global__ __launch_bounds__(256) void scan3(
    const int* __restrict__ excl, const int* __restrict__ bsum,
    int* __restrict__ row_ptr, int* __restrict__ row_cur, int n, int nnz)
{
    int i = blockIdx.x * 256 + threadIdx.x;
    if (i > n) return;
    if (i == n) { row_ptr[n] = nnz; return; }
    int v = excl[i] + bsum[i >> 10];
    row_ptr[i] = v;
    row_cur[i] = v;
}

__global__ __launch_bounds__(256) void scatter_csr(
    const int* __restrict__ row, const int* __restrict__ col,
    const float* __restrict__ val, int* __restrict__ row_cur,
    int* __restrict__ col_s, float* __restrict__ val_s, int nnz)
{
    int e = blockIdx.x * 256 + threadIdx.x;
    if (e >= nnz) return;
    int r = row[e];
    int p = atomicAdd(&row_cur[r], 1);
    col_s[p] = col[e];
    val_s[p] = val[e];
}

// ---------------------------------------------------------------------------
// Gather SpMM: one wave per row; 64 lanes = 4 edge-slots x 16 dim-groups.
// ---------------------------------------------------------------------------
__global__ __launch_bounds__(256) void spmm_gather(
    const int* __restrict__ row_ptr, const int* __restrict__ col_s,
    const float* __restrict__ val_s, const float* __restrict__ cur,
    float* __restrict__ nb)
{
    int t  = threadIdx.x;
    int wv = t >> 6;
    int l  = t & 63;
    int eg = l >> 4;          // edge slot 0..3
    int dg = l & 15;          // dim group (4 floats)
    int m = blockIdx.x * 4 + wv;
    if (m >= N_NODES) return;
    int beg = row_ptr[m], end = row_ptr[m + 1];
    float ax = 0.f, ay = 0.f, az = 0.f, aw = 0.f;
    for (int j = beg + eg; j < end; j += 4) {
        int   c = col_s[j];
        float v = val_s[j];
        float4 cv = *(const float4*)&cur[(size_t)c * 64 + dg * 4];
        ax += v * cv.x; ay += v * cv.y; az += v * cv.z; aw += v * cv.w;
    }
    ax += __shfl_xor(ax, 16, 64); ay += __shfl_xor(ay, 16, 64);
    az += __shfl_xor(az, 16, 64); aw += __shfl_xor(aw, 16, 64);
    ax += __shfl_xor(ax, 32, 64); ay += __shfl_xor(ay, 32, 64);
    az += __shfl_xor(az, 32, 64); aw += __shfl_xor(aw, 32, 64);
    if (eg == 0) {
        float4 r; r.x = ax; r.y = ay; r.z = az; r.w = aw;
        *(float4*)&nb[(size_t)m * 64 + dg * 4] = r;
    }
}

// ---------------------------------------------------------------------------
extern "C" void kernel_launch(void* const* d_in, const int* in_sizes, int n_in,
                              void* d_out, int out_size, void* d_ws, size_t ws_size,
                              hipStream_t stream)
{
    const int*   adj_row = (const int*)  d_in[0];
    const int*   adj_col = (const int*)  d_in[1];
    const float* adj_val = (const float*)d_in[2];
    const float* emb     = (const float*)d_in[3];
    const float* visf    = (const float*)d_in[4];
    const float* txtf    = (const float*)d_in[5];
    const float* Wv1 = (const float*)d_in[6];  const float* bv1 = (const float*)d_in[7];
    const float* Wv2 = (const float*)d_in[8];  const float* bv2 = (const float*)d_in[9];
    const float* Wt1 = (const float*)d_in[10]; const float* bt1 = (const float*)d_in[11];
    const float* Wt2 = (const float*)d_in[12]; const float* bt2 = (const float*)d_in[13];
    const float* Wd  = (const float*)d_in[14]; const float* bd  = (const float*)d_in[15];
    const float* Wc0 = (const float*)d_in[16]; const float* bc0 = (const float*)d_in[17];
    const float* Wc1 = (const float*)d_in[18]; const float* bc1 = (const float*)d_in[19];

    float* out = (float*)d_out;
    float* ws  = (float*)d_ws;

    // workspace layout (float offsets) — proven size, H1v2 aliases cur1
    float* H1v  = ws + 0;          // 10000*512
    float* H1t  = ws + 5120000;    // 10000*256
    float* nb   = ws + 0;          // 100000*64 (reuses H1v region, after MLP)
    float* s    = ws + 7680000;    // 10000*64
    float* cur0 = ws + 8320000;    // 100000*64
    float* cur1 = ws + 14720000;   // 100000*64
    float* H1v2 = ws + 14720000;   // 10000*512 partial plane 2 (aliases cur1;
                                   // consumed by linear64-vis BEFORE concat
                                   // layer1 writes cur1 -- stream-ordered)
    float* wv2T = ws + 21120000;   // 512*64
    float* wt2T = wv2T + 32768;    // 256*64
    float* wdT  = wt2T + 16384;    // 64*64
    int*   col_s   = (int*)  (ws + 21200000);  // 1.6M
    float* val_s   =          ws + 22800000;   // 1.6M
    int*   row_ptr = (int*)  (ws + 24400000);  // 100001
    int*   row_cur = (int*)  (ws + 24510000);  // 100000
    int*   cnt     = (int*)  (ws + 24620000);  // 100000
    int*   bsum    = (int*)  (ws + 24730000);  // 98

    const int NBLK = (N_NODES + 1023) / 1024;  // 98

    // ---- weight transposes (tiny) ----
    transp64<<<(64 * 512 + 255) / 256, 256, 0, stream>>>(Wv2, wv2T, 512);
    transp64<<<(64 * 256 + 255) / 256, 256, 0, stream>>>(Wt2, wt2T, 256);
    transp64<<<(64 * 64  + 255) / 256, 256, 0, stream>>>(Wd,  wdT,  64);

    // ---- CSR build (reused for both propagation layers) ----
    hipMemsetAsync(cnt, 0, N_NODES * sizeof(int), stream);
    hist_rows<<<(NNZ_E + 255) / 256, 256, 0, stream>>>(adj_row, cnt, NNZ_E);
    scan1<<<NBLK, 256, 0, stream>>>(cnt, bsum, N_NODES);
    scan2<<<1, 64, 0, stream>>>(bsum, NBLK);
    scan3<<<(N_NODES + 256) / 256, 256, 0, stream>>>(cnt, bsum, row_ptr, row_cur,
                                                     N_NODES, NNZ_E);
    scatter_csr<<<(NNZ_E + 255) / 256, 256, 0, stream>>>(adj_row, adj_col, adj_val,
                                                         row_cur, col_s, val_s, NNZ_E);

    // ---- item MLP layer 1: LDS-staged MFMA GEMMs, TN=64 tiles ----
    {
        // vis: M=10000 N=512 K=2048; K split in 2 planes (sum+relu fused
        // into linear64 consumer). 8 x 79 x 2 = 1264 blocks (~5/CU).
        dim3 g(512 / 64, (N_ITEMS + 127) / 128, 2);
        gemm_bf64<<<g, 256, 0, stream>>>(visf, Wv1, bv1, H1v,
                                         N_ITEMS, 512, VIS_DIM,
                                         1024, (long long)14720000, 0, 1);
    }
    {
        // txt: M=10000 N=256 K=300; no split, relu+bias in-kernel.
        // 4 x 79 = 316 blocks.
        dim3 g(256 / 64, (N_ITEMS + 127) / 128, 1);
        gemm_bf64<<<g, 256, 0, stream>>>(txtf, Wt1, bt1, H1t,
                                         N_ITEMS, 256, TXT_DIM,
                                         512, 0, 1, 1);
    }

    // ---- layer 2 + shared Wd (vis: fuse plane-sum + relu into consumer) ----
    linear64<<<(N_ITEMS + 15) / 16, 256, 0, stream>>>(H1v, H1v2, wv2T, bv2, s,
                                                      N_ITEMS, 512, 1.0f, 0, 1);
    linear64<<<(N_ITEMS + 15) / 16, 256, 0, stream>>>(H1t, nullptr, wt2T, bt2, s,
                                                      N_ITEMS, 256, 1.0f, 1, 0);
    linear64<<<(N_ITEMS + 15) / 16, 256, 0, stream>>>(s, nullptr, wdT, bd,
                                                      cur0 + (size_t)N_USERS * 64,
                                                      N_ITEMS, 64, 0.5f, 0, 0);

    // ---- assemble ego, write out[:, 0:64] ----
    ego_fill<<<(N_NODES * EMB + 255) / 256, 256, 0, stream>>>(emb, cur0, out);

    // ---- propagation layer 1 (gather SpMM + MFMA concat-linear) ----
    spmm_gather<<<(N_NODES + 3) / 4, 256, 0, stream>>>(row_ptr, col_s, val_s, cur0, nb);
    concat_mfma<<<(N_NODES + 127) / 128, 256, 0, stream>>>(cur0, nb, Wc0, bc0, cur1, out, 64);

    // ---- propagation layer 2 ----
    spmm_gather<<<(N_NODES + 3) / 4, 256, 0, stream>>>(row_ptr, col_s, val_s, cur1, nb);
    concat_mfma<<<(N_NODES + 127) / 128, 256, 0, stream>>>(cur1, nb, Wc1, bc1, nullptr, out, 128);
}

// Round 5
// 819.248 us; speedup vs baseline: 1.2049x; 1.0147x over previous
//
#include <hip/hip_runtime.h>
#include <hip/hip_bf16.h>
#include <cstddef>

#define N_USERS 50000
#define N_ITEMS 10000
#define N_NODES 100000
#define EMB 64
#define NNZ_E 1600000
#define VIS_DIM 2048
#define TXT_DIM 300

typedef short bf16x8 __attribute__((ext_vector_type(8)));
typedef float f32x4  __attribute__((ext_vector_type(4)));

__device__ inline unsigned short f2bf(float x) {
    __hip_bfloat16 h = __float2bfloat16(x);
    return __builtin_bit_cast(unsigned short, h);
}
__device__ inline float bf2f(unsigned short u) {
    unsigned int t = ((unsigned int)u) << 16;
    float f;
    __builtin_memcpy(&f, &t, 4);
    return f;
}

#define GLDW 40

// ---------------------------------------------------------------------------
// gemm_bf64: split-bf16 MFMA GEMM, C = act(A[M,K] @ W[N,K]^T + bias).
// TM=128, TN=64, BK=32, LDS-staged, 4 waves stacked in M (2x4 frags each),
// 3-term split (Ah*Wh + Ah*Wl + Al*Wh).
//
// XCD-aware 1D grid remap (R4 post-mortem): with the default x-fastest
// order, the 16 (n,z)-blocks sharing one m-tile's A rows round-robin
// across all 8 XCDs; per-XCD L2s are not coherent, so each XCD fetched
// the same 512KB A-slice independently -> FETCH_SIZE 323MB (= 79 m-tiles
// x 2 planes x 512KB x 8 XCDs), traffic-bound at 2.8 TB/s, 135us.
// Remap: wgid -> xcd = wgid&7, all (n,z) blocks of an m-tile share the
// same xcd residue -> A-slice fetched once per XCD. Grid must be a
// multiple of 8; tail m-tiles guarded (block-uniform early return).
//
// K-split: plane z writes C + z*c_plane (bias only on z==0, act must be 0);
// consumer (linear64 fuse path) sums planes + applies relu.
// ---------------------------------------------------------------------------
__global__ __launch_bounds__(256, 2) void gemm_bf64(
    const float* __restrict__ A, const float* __restrict__ W,
    const float* __restrict__ bias, float* __restrict__ C,
    int M, int N, int K, int k_per, long long c_plane,
    int act, int add_bias, int n_tiles, int m_tiles, int zsplit)
{
    __shared__ unsigned short Ah[128][GLDW], Al[128][GLDW];
    __shared__ unsigned short Bh[64][GLDW],  Bl[64][GLDW];

    // ---- XCD-aware block remap ----
    const int wg     = blockIdx.x;
    const int xcd    = wg & 7;
    const int rest   = wg >> 3;
    const int nzc    = n_tiles * zsplit;
    const int nz     = rest % nzc;
    const int mchunk = rest / nzc;
    const int mt     = xcd + (mchunk << 3);
    if (mt >= m_tiles) return;          // block-uniform
    const int nt     = nz % n_tiles;
    const int kz     = nz / n_tiles;

    const int t   = threadIdx.x;
    const int w   = t >> 6;
    const int l   = t & 63;
    const int l16 = l & 15;
    const int lq  = l >> 4;
    const int n0  = nt * 64;
    const int m0  = mt * 128;
    const int mh  = w * 32;

    const int kb  = kz * k_per;
    int krem = K - kb; if (krem > k_per) krem = k_per;
    const int kiters = (krem + 31) / 32;
    const int kend = kb + krem;
    float* Cz = C + (long long)kz * c_plane;

    // staging: A rows via chunks t (rows 0..63) and t+256 (rows 64..127);
    // W rows 0..63, one chunk per thread. 8 consecutive k-elems per chunk.
    const int rA0 = t >> 2;
    const int rA1 = (t + 256) >> 2;
    const int kc  = t & 3;

    f32x4 acc[2][4] = {};
    float pa[2][8], pw[8];

    auto load_tile = [&](int kt) {
        const int k0 = kb + kt * 32 + kc * 8;
        #pragma unroll
        for (int p = 0; p < 2; p++) {
            int rg = m0 + (p ? rA1 : rA0);
            if (rg >= M) rg = M - 1;
            const float* g = A + (size_t)rg * K + k0;
            if (k0 + 7 < kend) {
                float4 q0 = *(const float4*)g, q1 = *(const float4*)(g + 4);
                pa[p][0]=q0.x; pa[p][1]=q0.y; pa[p][2]=q0.z; pa[p][3]=q0.w;
                pa[p][4]=q1.x; pa[p][5]=q1.y; pa[p][6]=q1.z; pa[p][7]=q1.w;
            } else {
                #pragma unroll
                for (int i = 0; i < 8; i++)
                    pa[p][i] = (k0 + i < kend) ? g[i] : 0.f;
            }
        }
        int ng = n0 + rA0;
        if (ng >= N) ng = N - 1;
        const float* gw = W + (size_t)ng * K + k0;
        if (k0 + 7 < kend) {
            float4 q0 = *(const float4*)gw, q1 = *(const float4*)(gw + 4);
            pw[0]=q0.x; pw[1]=q0.y; pw[2]=q0.z; pw[3]=q0.w;
            pw[4]=q1.x; pw[5]=q1.y; pw[6]=q1.z; pw[7]=q1.w;
        } else {
            #pragma unroll
            for (int i = 0; i < 8; i++)
                pw[i] = (k0 + i < kend) ? gw[i] : 0.f;
        }
    };

    load_tile(0);

    for (int kt = 0; kt < kiters; kt++) {
        // ---- convert prefetched regs -> LDS hi/lo ----
        #pragma unroll
        for (int p = 0; p < 2; p++) {
            int row = p ? rA1 : rA0;
            bf16x8 hi, lo;
            #pragma unroll
            for (int i = 0; i < 8; i++) {
                unsigned short h = f2bf(pa[p][i]);
                hi[i] = (short)h;
                lo[i] = (short)f2bf(pa[p][i] - bf2f(h));
            }
            *(bf16x8*)&Ah[row][kc * 8] = hi;
            *(bf16x8*)&Al[row][kc * 8] = lo;
        }
        {
            bf16x8 hi, lo;
            #pragma unroll
            for (int i = 0; i < 8; i++) {
                unsigned short h = f2bf(pw[i]);
                hi[i] = (short)h;
                lo[i] = (short)f2bf(pw[i] - bf2f(h));
            }
            *(bf16x8*)&Bh[rA0][kc * 8] = hi;
            *(bf16x8*)&Bl[rA0][kc * 8] = lo;
        }
        __syncthreads();

        // ---- issue next tile's global loads (overlap with MFMA) ----
        if (kt + 1 < kiters) load_tile(kt + 1);

        // ---- MFMA: 2x4 frags x 3 split terms ----
        {
            bf16x8 ah[2], al[2];
            #pragma unroll
            for (int mi = 0; mi < 2; mi++) {
                ah[mi] = *(const bf16x8*)&Ah[mh + mi * 16 + l16][lq * 8];
                al[mi] = *(const bf16x8*)&Al[mh + mi * 16 + l16][lq * 8];
            }
            #pragma unroll
            for (int ni = 0; ni < 4; ni++) {
                bf16x8 bh = *(const bf16x8*)&Bh[ni * 16 + l16][lq * 8];
                bf16x8 bl = *(const bf16x8*)&Bl[ni * 16 + l16][lq * 8];
                #pragma unroll
                for (int mi = 0; mi < 2; mi++) {
                    acc[mi][ni] = __builtin_amdgcn_mfma_f32_16x16x32_bf16(
                        ah[mi], bh, acc[mi][ni], 0, 0, 0);
                    acc[mi][ni] = __builtin_amdgcn_mfma_f32_16x16x32_bf16(
                        ah[mi], bl, acc[mi][ni], 0, 0, 0);
                    acc[mi][ni] = __builtin_amdgcn_mfma_f32_16x16x32_bf16(
                        al[mi], bh, acc[mi][ni], 0, 0, 0);
                }
            }
        }
        __syncthreads();
    }

    // ---- epilogue ----
    #pragma unroll
    for (int ni = 0; ni < 4; ni++) {
        int col = n0 + ni * 16 + l16;
        if (col >= N) continue;
        float b = (add_bias && kz == 0) ? bias[col] : 0.f;
        #pragma unroll
        for (int mi = 0; mi < 2; mi++) {
            #pragma unroll
            for (int r = 0; r < 4; r++) {
                int row = m0 + mh + mi * 16 + lq * 4 + r;
                if (row >= M) continue;
                float v = acc[mi][ni][r] + b;
                if (act) v = fmaxf(v, 0.f);
                Cz[(size_t)row * N + col] = v;
            }
        }
    }
}

// ---------------------------------------------------------------------------
// concat_mfma: out[M,64] = leaky_relu([cur|nb][M,128] @ Wc[64,128]^T + bias)
// Split-bf16 3-term MFMA, TM=128, TN=64, BK=32, kiters=4.
// (No cross-block operand reuse -> no XCD swizzle needed here.)
// ---------------------------------------------------------------------------
__global__ __launch_bounds__(256, 2) void concat_mfma(
    const float* __restrict__ cur, const float* __restrict__ nbuf,
    const float* __restrict__ Wc, const float* __restrict__ bias,
    float* __restrict__ out_cur, float* __restrict__ out_full, int col_off)
{
    __shared__ unsigned short Ah[128][GLDW], Al[128][GLDW];
    __shared__ unsigned short Bh[64][GLDW],  Bl[64][GLDW];

    const int t   = threadIdx.x;
    const int w   = t >> 6;
    const int l   = t & 63;
    const int l16 = l & 15;
    const int lq  = l >> 4;
    const int m0  = blockIdx.x * 128;
    const int mh  = w * 32;

    const int r  = t >> 2;
    const int kc = t & 3;

    f32x4 acc[2][4] = {};

    float pa[2][8], pw[8];

    auto load_tile = [&](int kt) {
        const float* src = (kt < 2) ? cur : nbuf;
        const int kcol = (kt & 1) * 32 + kc * 8;
        #pragma unroll
        for (int p = 0; p < 2; p++) {
            int rg = m0 + r + p * 64;
            if (rg >= N_NODES) rg = N_NODES - 1;
            const float* g = src + (size_t)rg * 64 + kcol;
            float4 q0 = *(const float4*)g, q1 = *(const float4*)(g + 4);
            pa[p][0]=q0.x; pa[p][1]=q0.y; pa[p][2]=q0.z; pa[p][3]=q0.w;
            pa[p][4]=q1.x; pa[p][5]=q1.y; pa[p][6]=q1.z; pa[p][7]=q1.w;
        }
        const float* gw = Wc + (size_t)r * 128 + kt * 32 + kc * 8;
        float4 q0 = *(const float4*)gw, q1 = *(const float4*)(gw + 4);
        pw[0]=q0.x; pw[1]=q0.y; pw[2]=q0.z; pw[3]=q0.w;
        pw[4]=q1.x; pw[5]=q1.y; pw[6]=q1.z; pw[7]=q1.w;
    };

    load_tile(0);

    for (int kt = 0; kt < 4; kt++) {
        #pragma unroll
        for (int p = 0; p < 2; p++) {
            bf16x8 hi, lo;
            #pragma unroll
            for (int i = 0; i < 8; i++) {
                unsigned short h = f2bf(pa[p][i]);
                hi[i] = (short)h;
                lo[i] = (short)f2bf(pa[p][i] - bf2f(h));
            }
            *(bf16x8*)&Ah[r + p * 64][kc * 8] = hi;
            *(bf16x8*)&Al[r + p * 64][kc * 8] = lo;
        }
        {
            bf16x8 hi, lo;
            #pragma unroll
            for (int i = 0; i < 8; i++) {
                unsigned short h = f2bf(pw[i]);
                hi[i] = (short)h;
                lo[i] = (short)f2bf(pw[i] - bf2f(h));
            }
            *(bf16x8*)&Bh[r][kc * 8] = hi;
            *(bf16x8*)&Bl[r][kc * 8] = lo;
        }
        __syncthreads();

        if (kt < 3) load_tile(kt + 1);

        {
            bf16x8 ah[2], al[2];
            #pragma unroll
            for (int mi = 0; mi < 2; mi++) {
                ah[mi] = *(const bf16x8*)&Ah[mh + mi * 16 + l16][lq * 8];
                al[mi] = *(const bf16x8*)&Al[mh + mi * 16 + l16][lq * 8];
            }
            #pragma unroll
            for (int ni = 0; ni < 4; ni++) {
                bf16x8 bh = *(const bf16x8*)&Bh[ni * 16 + l16][lq * 8];
                bf16x8 bl = *(const bf16x8*)&Bl[ni * 16 + l16][lq * 8];
                #pragma unroll
                for (int mi = 0; mi < 2; mi++) {
                    acc[mi][ni] = __builtin_amdgcn_mfma_f32_16x16x32_bf16(
                        ah[mi], bh, acc[mi][ni], 0, 0, 0);
                    acc[mi][ni] = __builtin_amdgcn_mfma_f32_16x16x32_bf16(
                        ah[mi], bl, acc[mi][ni], 0, 0, 0);
                    acc[mi][ni] = __builtin_amdgcn_mfma_f32_16x16x32_bf16(
                        al[mi], bh, acc[mi][ni], 0, 0, 0);
                }
            }
        }
        __syncthreads();
    }

    #pragma unroll
    for (int ni = 0; ni < 4; ni++) {
        int col = ni * 16 + l16;
        float bcol = bias[col];
        #pragma unroll
        for (int mi = 0; mi < 2; mi++) {
            #pragma unroll
            for (int rr = 0; rr < 4; rr++) {
                int row = m0 + mh + mi * 16 + lq * 4 + rr;
                if (row >= N_NODES) continue;
                float v = acc[mi][ni][rr] + bcol;
                v = (v > 0.f) ? v : 0.01f * v;
                if (out_cur) out_cur[(size_t)row * 64 + col] = v;
                out_full[(size_t)row * 192 + col_off + col] = v;
            }
        }
    }
}

// ---------------------------------------------------------------------------
__global__ void transp64(const float* __restrict__ W, float* __restrict__ wT, int K)
{
    int i = blockIdx.x * 256 + threadIdx.x;
    if (i >= 64 * K) return;
    int d = i / K, k = i - d * K;
    wT[k * 64 + d] = W[i];
}

// ---------------------------------------------------------------------------
// linear64 v3: out[M,64] = f(in [+ in2])[M,K] @ wT[K,64] * in_scale + bias.
// fuse_relu: sums two partial K-split planes and applies relu on the fly.
// ---------------------------------------------------------------------------
__global__ __launch_bounds__(256) void linear64(
    const float* __restrict__ in, const float* __restrict__ in2,
    const float* __restrict__ wT, const float* __restrict__ bias,
    float* __restrict__ out, int M, int K, float in_scale, int add,
    int fuse_relu)
{
    int t  = threadIdx.x;
    int d  = t & 63;
    int w  = t >> 6;
    int m0 = blockIdx.x * 16 + w * 4;
    if (m0 >= M) return;
    int mlast = M - 1;
    int m1 = (m0 + 1 < M) ? m0 + 1 : mlast;
    int m2 = (m0 + 2 < M) ? m0 + 2 : mlast;
    int m3 = (m0 + 3 < M) ? m0 + 3 : mlast;

    const float* x0 = in + (size_t)m0 * K;
    const float* x1 = in + (size_t)m1 * K;
    const float* x2 = in + (size_t)m2 * K;
    const float* x3 = in + (size_t)m3 * K;
    const float* y0 = fuse_relu ? in2 + (size_t)m0 * K : x0;
    const float* y1 = fuse_relu ? in2 + (size_t)m1 * K : x1;
    const float* y2 = fuse_relu ? in2 + (size_t)m2 * K : x2;
    const float* y3 = fuse_relu ? in2 + (size_t)m3 * K : x3;

    float a0 = 0.f, a1 = 0.f, a2 = 0.f, a3 = 0.f;

    for (int k = 0; k < K; k += 8) {
        const float* wp = wT + (size_t)k * 64 + d;
        float w0 = wp[0],   w1 = wp[64],  w2 = wp[128], w3 = wp[192];
        float w4 = wp[256], w5 = wp[320], w6 = wp[384], w7 = wp[448];
        float4 p0 = *(const float4*)(x0 + k), q0 = *(const float4*)(x0 + k + 4);
        float4 p1 = *(const float4*)(x1 + k), q1 = *(const float4*)(x1 + k + 4);
        float4 p2 = *(const float4*)(x2 + k), q2 = *(const float4*)(x2 + k + 4);
        float4 p3 = *(const float4*)(x3 + k), q3 = *(const float4*)(x3 + k + 4);
        if (fuse_relu) {
            float4 r0 = *(const float4*)(y0 + k), s0 = *(const float4*)(y0 + k + 4);
            float4 r1 = *(const float4*)(y1 + k), s1 = *(const float4*)(y1 + k + 4);
            float4 r2 = *(const float4*)(y2 + k), s2 = *(const float4*)(y2 + k + 4);
            float4 r3 = *(const float4*)(y3 + k), s3 = *(const float4*)(y3 + k + 4);
            p0.x=fmaxf(p0.x+r0.x,0.f); p0.y=fmaxf(p0.y+r0.y,0.f);
            p0.z=fmaxf(p0.z+r0.z,0.f); p0.w=fmaxf(p0.w+r0.w,0.f);
            q0.x=fmaxf(q0.x+s0.x,0.f); q0.y=fmaxf(q0.y+s0.y,0.f);
            q0.z=fmaxf(q0.z+s0.z,0.f); q0.w=fmaxf(q0.w+s0.w,0.f);
            p1.x=fmaxf(p1.x+r1.x,0.f); p1.y=fmaxf(p1.y+r1.y,0.f);
            p1.z=fmaxf(p1.z+r1.z,0.f); p1.w=fmaxf(p1.w+r1.w,0.f);
            q1.x=fmaxf(q1.x+s1.x,0.f); q1.y=fmaxf(q1.y+s1.y,0.f);
            q1.z=fmaxf(q1.z+s1.z,0.f); q1.w=fmaxf(q1.w+s1.w,0.f);
            p2.x=fmaxf(p2.x+r2.x,0.f); p2.y=fmaxf(p2.y+r2.y,0.f);
            p2.z=fmaxf(p2.z+r2.z,0.f); p2.w=fmaxf(p2.w+r2.w,0.f);
            q2.x=fmaxf(q2.x+s2.x,0.f); q2.y=fmaxf(q2.y+s2.y,0.f);
            q2.z=fmaxf(q2.z+s2.z,0.f); q2.w=fmaxf(q2.w+s2.w,0.f);
            p3.x=fmaxf(p3.x+r3.x,0.f); p3.y=fmaxf(p3.y+r3.y,0.f);
            p3.z=fmaxf(p3.z+r3.z,0.f); p3.w=fmaxf(p3.w+r3.w,0.f);
            q3.x=fmaxf(q3.x+s3.x,0.f); q3.y=fmaxf(q3.y+s3.y,0.f);
            q3.z=fmaxf(q3.z+s3.z,0.f); q3.w=fmaxf(q3.w+s3.w,0.f);
        }
        a0 += p0.x*w0 + p0.y*w1 + p0.z*w2 + p0.w*w3
            + q0.x*w4 + q0.y*w5 + q0.z*w6 + q0.w*w7;
        a1 += p1.x*w0 + p1.y*w1 + p1.z*w2 + p1.w*w3
            + q1.x*w4 + q1.y*w5 + q1.z*w6 + q1.w*w7;
        a2 += p2.x*w0 + p2.y*w1 + p2.z*w2 + p2.w*w3
            + q2.x*w4 + q2.y*w5 + q2.z*w6 + q2.w*w7;
        a3 += p3.x*w0 + p3.y*w1 + p3.z*w2 + p3.w*w3
            + q3.x*w4 + q3.y*w5 + q3.z*w6 + q3.w*w7;
    }

    float b = bias[d];
    float r0 = a0 * in_scale + b;
    float r1 = a1 * in_scale + b;
    float r2 = a2 * in_scale + b;
    float r3 = a3 * in_scale + b;
    if (add) {
        out[(size_t)m0 * 64 + d] += r0;
        if (m0 + 1 < M) out[(size_t)m1 * 64 + d] += r1;
        if (m0 + 2 < M) out[(size_t)m2 * 64 + d] += r2;
        if (m0 + 3 < M) out[(size_t)m3 * 64 + d] += r3;
    } else {
        out[(size_t)m0 * 64 + d] = r0;
        if (m0 + 1 < M) out[(size_t)m1 * 64 + d] = r1;
        if (m0 + 2 < M) out[(size_t)m2 * 64 + d] = r2;
        if (m0 + 3 < M) out[(size_t)m3 * 64 + d] = r3;
    }
}

// ---------------------------------------------------------------------------
__global__ void ego_fill(const float* __restrict__ emb, float* __restrict__ cur0,
                         float* __restrict__ out_full)
{
    int tid = blockIdx.x * 256 + threadIdx.x;
    if (tid >= N_NODES * EMB) return;
    int m = tid >> 6, d = tid & 63;
    float v;
    if (m < N_USERS || m >= N_USERS + N_ITEMS) {
        v = emb[tid];
        cur0[tid] = v;
    } else {
        v = cur0[tid];
    }
    out_full[(size_t)m * 192 + d] = v;
}

// ---------------------------------------------------------------------------
// CSR build: histogram -> exclusive scan -> scatter
// ---------------------------------------------------------------------------
__global__ __launch_bounds__(256) void hist_rows(
    const int* __restrict__ row, int* __restrict__ cnt, int nnz)
{
    int e = blockIdx.x * 256 + threadIdx.x;
    if (e >= nnz) return;
    atomicAdd(&cnt[row[e]], 1);
}

__global__ __launch_bounds__(256) void scan1(int* __restrict__ cnt,
                                             int* __restrict__ bsum, int n)
{
    __shared__ int part[256];
    int t = threadIdx.x;
    int base = blockIdx.x * 1024 + t * 4;
    int v0 = 0, v1 = 0, v2 = 0, v3 = 0;
    if (base + 0 < n) v0 = cnt[base + 0];
    if (base + 1 < n) v1 = cnt[base + 1];
    if (base + 2 < n) v2 = cnt[base + 2];
    if (base + 3 < n) v3 = cnt[base + 3];
    int s = v0 + v1 + v2 + v3;
    part[t] = s;
    __syncthreads();
    for (int off = 1; off < 256; off <<= 1) {
        int x = (t >= off) ? part[t - off] : 0;
        __syncthreads();
        part[t] += x;
        __syncthreads();
    }
    int excl = part[t] - s;
    if (t == 255) bsum[blockIdx.x] = part[t];
    if (base + 0 < n) cnt[base + 0] = excl;
    if (base + 1 < n) cnt[base + 1] = excl + v0;
    if (base + 2 < n) cnt[base + 2] = excl + v0 + v1;
    if (base + 3 < n) cnt[base + 3] = excl + v0 + v1 + v2;
}

__global__ void scan2(int* __restrict__ bsum, int nb)
{
    if (threadIdx.x == 0 && blockIdx.x == 0) {
        int acc = 0;
        for (int i = 0; i < nb; i++) { int v = bsum[i]; bsum[i] = acc; acc += v; }
    }
}

__global__ __launch_bounds__(256) void scan3(
    const int* __restrict__ excl, const int* __restrict__ bsum,
    int* __restrict__ row_ptr, int* __restrict__ row_cur, int n, int nnz)
{
    int i = blockIdx.x * 256 + threadIdx.x;
    if (i > n) return;
    if (i == n) { row_ptr[n] = nnz; return; }
    int v = excl[i] + bsum[i >> 10];
    row_ptr[i] = v;
    row_cur[i] = v;
}

__global__ __launch_bounds__(256) void scatter_csr(
    const int* __restrict__ row, const int* __restrict__ col,
    const float* __restrict__ val, int* __restrict__ row_cur,
    int* __restrict__ col_s, float* __restrict__ val_s, int nnz)
{
    int e = blockIdx.x * 256 + threadIdx.x;
    if (e >= nnz) return;
    int r = row[e];
    int p = atomicAdd(&row_cur[r], 1);
    col_s[p] = col[e];
    val_s[p] = val[e];
}

// ---------------------------------------------------------------------------
// Gather SpMM: one wave per row; 64 lanes = 4 edge-slots x 16 dim-groups.
// ---------------------------------------------------------------------------
__global__ __launch_bounds__(256) void spmm_gather(
    const int* __restrict__ row_ptr, const int* __restrict__ col_s,
    const float* __restrict__ val_s, const float* __restrict__ cur,
    float* __restrict__ nb)
{
    int t  = threadIdx.x;
    int wv = t >> 6;
    int l  = t & 63;
    int eg = l >> 4;          // edge slot 0..3
    int dg = l & 15;          // dim group (4 floats)
    int m = blockIdx.x * 4 + wv;
    if (m >= N_NODES) return;
    int beg = row_ptr[m], end = row_ptr[m + 1];
    float ax = 0.f, ay = 0.f, az = 0.f, aw = 0.f;
    for (int j = beg + eg; j < end; j += 4) {
        int   c = col_s[j];
        float v = val_s[j];
        float4 cv = *(const float4*)&cur[(size_t)c * 64 + dg * 4];
        ax += v * cv.x; ay += v * cv.y; az += v * cv.z; aw += v * cv.w;
    }
    ax += __shfl_xor(ax, 16, 64); ay += __shfl_xor(ay, 16, 64);
    az += __shfl_xor(az, 16, 64); aw += __shfl_xor(aw, 16, 64);
    ax += __shfl_xor(ax, 32, 64); ay += __shfl_xor(ay, 32, 64);
    az += __shfl_xor(az, 32, 64); aw += __shfl_xor(aw, 32, 64);
    if (eg == 0) {
        float4 r; r.x = ax; r.y = ay; r.z = az; r.w = aw;
        *(float4*)&nb[(size_t)m * 64 + dg * 4] = r;
    }
}

// ---------------------------------------------------------------------------
extern "C" void kernel_launch(void* const* d_in, const int* in_sizes, int n_in,
                              void* d_out, int out_size, void* d_ws, size_t ws_size,
                              hipStream_t stream)
{
    const int*   adj_row = (const int*)  d_in[0];
    const int*   adj_col = (const int*)  d_in[1];
    const float* adj_val = (const float*)d_in[2];
    const float* emb     = (const float*)d_in[3];
    const float* visf    = (const float*)d_in[4];
    const float* txtf    = (const float*)d_in[5];
    const float* Wv1 = (const float*)d_in[6];  const float* bv1 = (const float*)d_in[7];
    const float* Wv2 = (const float*)d_in[8];  const float* bv2 = (const float*)d_in[9];
    const float* Wt1 = (const float*)d_in[10]; const float* bt1 = (const float*)d_in[11];
    const float* Wt2 = (const float*)d_in[12]; const float* bt2 = (const float*)d_in[13];
    const float* Wd  = (const float*)d_in[14]; const float* bd  = (const float*)d_in[15];
    const float* Wc0 = (const float*)d_in[16]; const float* bc0 = (const float*)d_in[17];
    const float* Wc1 = (const float*)d_in[18]; const float* bc1 = (const float*)d_in[19];

    float* out = (float*)d_out;
    float* ws  = (float*)d_ws;

    // workspace layout (float offsets) — proven size, H1v2 aliases cur1
    float* H1v  = ws + 0;          // 10000*512
    float* H1t  = ws + 5120000;    // 10000*256
    float* nb   = ws + 0;          // 100000*64 (reuses H1v region, after MLP)
    float* s    = ws + 7680000;    // 10000*64
    float* cur0 = ws + 8320000;    // 100000*64
    float* cur1 = ws + 14720000;   // 100000*64
    float* H1v2 = ws + 14720000;   // 10000*512 partial plane 2 (aliases cur1;
                                   // consumed by linear64-vis BEFORE concat
                                   // layer1 writes cur1 -- stream-ordered)
    float* wv2T = ws + 21120000;   // 512*64
    float* wt2T = wv2T + 32768;    // 256*64
    float* wdT  = wt2T + 16384;    // 64*64
    int*   col_s   = (int*)  (ws + 21200000);  // 1.6M
    float* val_s   =          ws + 22800000;   // 1.6M
    int*   row_ptr = (int*)  (ws + 24400000);  // 100001
    int*   row_cur = (int*)  (ws + 24510000);  // 100000
    int*   cnt     = (int*)  (ws + 24620000);  // 100000
    int*   bsum    = (int*)  (ws + 24730000);  // 98

    const int NBLK = (N_NODES + 1023) / 1024;  // 98

    // ---- weight transposes (tiny) ----
    transp64<<<(64 * 512 + 255) / 256, 256, 0, stream>>>(Wv2, wv2T, 512);
    transp64<<<(64 * 256 + 255) / 256, 256, 0, stream>>>(Wt2, wt2T, 256);
    transp64<<<(64 * 64  + 255) / 256, 256, 0, stream>>>(Wd,  wdT,  64);

    // ---- CSR build (reused for both propagation layers) ----
    hipMemsetAsync(cnt, 0, N_NODES * sizeof(int), stream);
    hist_rows<<<(NNZ_E + 255) / 256, 256, 0, stream>>>(adj_row, cnt, NNZ_E);
    scan1<<<NBLK, 256, 0, stream>>>(cnt, bsum, N_NODES);
    scan2<<<1, 64, 0, stream>>>(bsum, NBLK);
    scan3<<<(N_NODES + 256) / 256, 256, 0, stream>>>(cnt, bsum, row_ptr, row_cur,
                                                     N_NODES, NNZ_E);
    scatter_csr<<<(NNZ_E + 255) / 256, 256, 0, stream>>>(adj_row, adj_col, adj_val,
                                                         row_cur, col_s, val_s, NNZ_E);

    // ---- item MLP layer 1: LDS-staged MFMA GEMMs, XCD-swizzled 1D grid ----
    {
        // vis: M=10000 N=512 K=2048; 8 n-tiles x 79 m-tiles x 2 k-planes.
        // grid = 8 xcd-residues * (8*2) nz * ceil(79/8) = 1280 blocks.
        int n_tiles = 8, m_tiles = 79, zsplit = 2;
        int grid = 8 * n_tiles * zsplit * ((m_tiles + 7) / 8);
        gemm_bf64<<<grid, 256, 0, stream>>>(visf, Wv1, bv1, H1v,
                                            N_ITEMS, 512, VIS_DIM,
                                            1024, (long long)14720000, 0, 1,
                                            n_tiles, m_tiles, zsplit);
    }
    {
        // txt: M=10000 N=256 K=300; 4 n-tiles, no k-split, relu+bias here.
        int n_tiles = 4, m_tiles = 79, zsplit = 1;
        int grid = 8 * n_tiles * zsplit * ((m_tiles + 7) / 8);
        gemm_bf64<<<grid, 256, 0, stream>>>(txtf, Wt1, bt1, H1t,
                                            N_ITEMS, 256, TXT_DIM,
                                            512, 0, 1, 1,
                                            n_tiles, m_tiles, zsplit);
    }

    // ---- layer 2 + shared Wd (vis: fuse plane-sum + relu into consumer) ----
    linear64<<<(N_ITEMS + 15) / 16, 256, 0, stream>>>(H1v, H1v2, wv2T, bv2, s,
                                                      N_ITEMS, 512, 1.0f, 0, 1);
    linear64<<<(N_ITEMS + 15) / 16, 256, 0, stream>>>(H1t, nullptr, wt2T, bt2, s,
                                                      N_ITEMS, 256, 1.0f, 1, 0);
    linear64<<<(N_ITEMS + 15) / 16, 256, 0, stream>>>(s, nullptr, wdT, bd,
                                                      cur0 + (size_t)N_USERS * 64,
                                                      N_ITEMS, 64, 0.5f, 0, 0);

    // ---- assemble ego, write out[:, 0:64] ----
    ego_fill<<<(N_NODES * EMB + 255) / 256, 256, 0, stream>>>(emb, cur0, out);

    // ---- propagation layer 1 (gather SpMM + MFMA concat-linear) ----
    spmm_gather<<<(N_NODES + 3) / 4, 256, 0, stream>>>(row_ptr, col_s, val_s, cur0, nb);
    concat_mfma<<<(N_NODES + 127) / 128, 256, 0, stream>>>(cur0, nb, Wc0, bc0, cur1, out, 64);

    // ---- propagation layer 2 ----
    spmm_gather<<<(N_NODES + 3) / 4, 256, 0, stream>>>(row_ptr, col_s, val_s, cur1, nb);
    concat_mfma<<<(N_NODES + 127) / 128, 256, 0, stream>>>(cur1, nb, Wc1, bc1, nullptr, out, 128);
}